// Round 12
// baseline (141.041 us; speedup 1.0000x reference)
//
#include <hip/hip_runtime.h>

typedef __bf16 bf16;
typedef __bf16 bf16x4 __attribute__((ext_vector_type(4)));
typedef __bf16 bf16x8 __attribute__((ext_vector_type(8)));
typedef float  f32x4  __attribute__((ext_vector_type(4)));

#define SCALE 0.17677669529663687f  // 32^-0.5

// ws layout (bytes)
#define XWIN_OFF  0                  // bf16 [64 b][64 win][64 tok][96 ch]
#define WQKVT_OFF 50331648           // bf16 [288][96] (q cols pre-scaled)
#define WOUTT_OFF 50386944           // bf16 [96][96] transposed
#define BIASC_OFF 50405376           // f32 [3 h][4 ni][4 w][64 lane][4 e] C-frag layout

// Compiler-only barrier: intra-wave LDS RAW/WAR is safe on the in-order DS
// pipe; we only need to stop the COMPILER from reordering smem accesses.
#define CBAR() asm volatile("" ::: "memory")

// 16-lane (DPP row) all-reduce; ctrl must be a compile-time constant.
template <int CTRL>
__device__ __forceinline__ float dpp_mv(float x) {
    return __int_as_float(__builtin_amdgcn_update_dpp(
        0, __float_as_int(x), CTRL, 0xF, 0xF, true));
}
__device__ __forceinline__ float row16_max(float m) {
    m = fmaxf(m, dpp_mv<0xB1>(m));   // quad_perm [1,0,3,2]
    m = fmaxf(m, dpp_mv<0x4E>(m));   // quad_perm [2,3,0,1]
    m = fmaxf(m, dpp_mv<0x124>(m));  // row_ror:4
    m = fmaxf(m, dpp_mv<0x128>(m));  // row_ror:8
    return m;
}
__device__ __forceinline__ float row16_sum(float s) {
    s += dpp_mv<0xB1>(s);
    s += dpp_mv<0x4E>(s);
    s += dpp_mv<0x124>(s);
    s += dpp_mv<0x128>(s);
    return s;
}

// ---- im2win (blocks 0..511) + weight/bias prep (blocks 512..515)
__global__ __launch_bounds__(512)
void pre(const float* __restrict__ x, const float* __restrict__ wqkv,
         const float* __restrict__ pos, const float* __restrict__ wout,
         bf16* __restrict__ xwin, bf16* __restrict__ wqkvT,
         bf16* __restrict__ woutT, float* __restrict__ biasC)
{
    __shared__ bf16 xs[392 * 50];
    if (blockIdx.x < 512) {
        const int tid = threadIdx.x;
        const int b = blockIdx.x >> 3, wh = blockIdx.x & 7;
        const float* xb = x + (size_t)b * 96 * 3136 + wh * 7 * 56;
        bf16* xo = xwin + ((size_t)b * 64 + wh * 8) * 64 * 96;
        for (int c0 = 0; c0 < 96; c0 += 48) {
            if (c0) __syncthreads();
            for (int i = tid; i < 48 * 392; i += 512) {
                int c = i / 392, t = i - c * 392;
                xs[t * 50 + c] = (bf16)xb[(size_t)(c0 + c) * 3136 + t];
            }
            __syncthreads();
            for (int i = tid; i < 8 * 64 * 48; i += 512) {
                int c = i % 48;
                int wt = (i / 48) & 63;
                int win = i / (48 * 64);
                bf16 v = (bf16)0.f;
                if (wt < 49) v = xs[((wt / 7) * 56 + win * 7 + (wt % 7)) * 50 + c];
                xo[(win * 64 + wt) * 96 + c0 + c] = v;
            }
        }
    } else {
        int tid = (blockIdx.x - 512) * 512 + threadIdx.x;
        const int stride = 4 * 512;
        for (int i = tid; i < 288 * 96; i += stride) {
            int n = i / 96, c = i % 96;
            float v = wqkv[c * 288 + n];
            if (n < 96) v *= SCALE;
            wqkvT[i] = (bf16)v;
        }
        for (int i = tid; i < 96 * 96; i += stride) {
            int o = i / 96, c = i % 96;
            woutT[i] = (bf16)wout[c * 96 + o];
        }
        // biasC[h][ni][w][lane][e] at row=w*16+(lane>>4)*4+e, col=ni*16+(lane&15)
        for (int i = tid; i < 3 * 4 * 4 * 64 * 4; i += stride) {
            int e = i & 3, lane = (i >> 2) & 63, wv = (i >> 8) & 3, ni = (i >> 10) & 3, h = i >> 12;
            int row = wv * 16 + ((lane >> 4) << 2) + e;
            int col = ni * 16 + (lane & 15);
            float v;
            if (col >= 49) v = -1e30f;
            else if (row >= 49) v = 0.f;
            else {
                int ridx = ((col / 7) - (row / 7) + 6) * 13 + ((col % 7) - (row % 7) + 6);
                v = pos[ridx * 3 + h];
            }
            biasC[i] = v;
        }
    }
}

// One block (4 waves) per window; wave w owns token strip w*16..+15.
// LDS 40448 B -> 4 blocks/CU. 3 __syncthreads; intra-wave phases use CBAR only.
__global__ __launch_bounds__(256, 4)
void winattn(const bf16* __restrict__ xwin, const float* __restrict__ bout,
             const bf16* __restrict__ wqkvT, const bf16* __restrict__ woutT,
             const float* __restrict__ biasC, float* __restrict__ out)
{
    __shared__ __align__(16) unsigned char smem[40448];
    bf16* qall = (bf16*)(smem);          // [64][104]
    bf16* kall = (bf16*)(smem + 13312);  // [64][104]
    bf16* vt   = (bf16*)(smem + 26624);  // [96][72]
    bf16* Ost  = (bf16*)(smem);          // overlay qall (own strip only)
    float* fin = (float*)(smem + 13312); // [64][101] f32, overlays kall+vt (post-B2)

    const int tid = threadIdx.x;
    const int w = tid >> 6, lane = tid & 63;
    const int lr = lane & 15, lk = lane >> 4;

    const int blk = blockIdx.x;
    const int b = blk >> 6, win = blk & 63;
    const int row0 = (win >> 3) * 7, col0 = (win & 7) * 7;
    const bf16* xg = xwin + (size_t)blk * 64 * 96;

    float bo[6];
#pragma unroll
    for (int ni = 0; ni < 6; ++ni) bo[ni] = bout[ni * 16 + lr];

    // ---- QKV: wave w = row strip; 3 groups of 6 ni tiles (g0=q, g1=k, g2=v)
    {
        bf16x8 a[3];
#pragma unroll
        for (int k = 0; k < 3; ++k)
            a[k] = *(const bf16x8*)&xg[(w * 16 + lr) * 96 + k * 32 + lk * 8];
#pragma unroll
        for (int g = 0; g < 3; ++g) {
            f32x4 acc[6];
#pragma unroll
            for (int j = 0; j < 6; ++j) acc[j] = (f32x4){0.f, 0.f, 0.f, 0.f};
#pragma unroll
            for (int k = 0; k < 3; ++k)
#pragma unroll
                for (int j = 0; j < 6; ++j) {
                    bf16x8 bb = *(const bf16x8*)&wqkvT[((g * 6 + j) * 16 + lr) * 96 + k * 32 + lk * 8];
                    acc[j] = __builtin_amdgcn_mfma_f32_16x16x32_bf16(a[k], bb, acc[j], 0, 0, 0);
                }
            if (g == 0) {
#pragma unroll
                for (int j = 0; j < 6; ++j)
#pragma unroll
                    for (int e = 0; e < 4; ++e)
                        qall[(w * 16 + lk * 4 + e) * 104 + j * 16 + lr] = (bf16)acc[j][e];
            } else if (g == 1) {
#pragma unroll
                for (int j = 0; j < 6; ++j)
#pragma unroll
                    for (int e = 0; e < 4; ++e)
                        kall[(w * 16 + lk * 4 + e) * 104 + j * 16 + lr] = (bf16)acc[j][e];
            } else {
#pragma unroll
                for (int j = 0; j < 6; ++j) {
                    bf16x4 pk;
#pragma unroll
                    for (int e = 0; e < 4; ++e) pk[e] = (bf16)acc[j][e];
                    *(bf16x4*)&vt[(j * 16 + lr) * 72 + w * 16 + lk * 4] = pk;
                }
            }
        }
    }
    // prefetch head-0 bias C-frags (latency covered by barrier)
    f32x4 bias0[4], bias1[4], bias2[4];
#pragma unroll
    for (int ni = 0; ni < 4; ++ni)
        bias0[ni] = *(const f32x4*)&biasC[(size_t)((0 * 4 + ni) * 4 + w) * 256 + lane * 4];
    __syncthreads();   // B1

    // ---- read Q A-frags for all heads; then P may overlay own qall strip
    bf16x8 qa[3];
#pragma unroll
    for (int h = 0; h < 3; ++h)
        qa[h] = *(const bf16x8*)&qall[(w * 16 + lr) * 104 + h * 32 + lk * 8];
    CBAR();   // in-order DS pipe handles the WAR vs Pw writes

    bf16* Pw = (bf16*)(smem + w * 3328);   // [16][72] inside own qall strip

    f32x4 oacc[3][2];
    float inv[3][4];
#pragma unroll
    for (int h = 0; h < 3; ++h)
#pragma unroll
        for (int ni = 0; ni < 2; ++ni) oacc[h][ni] = (f32x4){0.f, 0.f, 0.f, 0.f};

#pragma unroll
    for (int h = 0; h < 3; ++h) {
        // S = Q@K^T + bias (bias is the C-operand)
        f32x4 sacc[4];
        const f32x4* bc = (h == 0) ? bias0 : (h == 1) ? bias1 : bias2;
#pragma unroll
        for (int ni = 0; ni < 4; ++ni) {
            bf16x8 kb = *(const bf16x8*)&kall[(ni * 16 + lr) * 104 + h * 32 + lk * 8];
            sacc[ni] = __builtin_amdgcn_mfma_f32_16x16x32_bf16(qa[h], kb, bc[ni], 0, 0, 0);
        }
        // prefetch next head's bias (covered by softmax+PV)
        if (h == 0) {
#pragma unroll
            for (int ni = 0; ni < 4; ++ni)
                bias1[ni] = *(const f32x4*)&biasC[(size_t)((1 * 4 + ni) * 4 + w) * 256 + lane * 4];
        } else if (h == 1) {
#pragma unroll
            for (int ni = 0; ni < 4; ++ni)
                bias2[ni] = *(const f32x4*)&biasC[(size_t)((2 * 4 + ni) * 4 + w) * 256 + lane * 4];
        }
        // softmax over 64 cols: 4 regs local + DPP 16-lane all-reduce.
        // P stored UNNORMALIZED (<=1); inv folded into the Ost write.
#pragma unroll
        for (int e = 0; e < 4; ++e) {
            float s0 = sacc[0][e], s1 = sacc[1][e], s2 = sacc[2][e], s3 = sacc[3][e];
            float m = row16_max(fmaxf(fmaxf(s0, s1), fmaxf(s2, s3)));
            float p0 = __expf(s0 - m), p1 = __expf(s1 - m);
            float p2 = __expf(s2 - m), p3 = __expf(s3 - m);
            float s = row16_sum((p0 + p1) + (p2 + p3));
            inv[h][e] = __builtin_amdgcn_rcpf(s);
            int rl = lk * 4 + e;
            Pw[rl * 72 + lr]      = (bf16)p0;
            Pw[rl * 72 + 16 + lr] = (bf16)p1;
            Pw[rl * 72 + 32 + lr] = (bf16)p2;
            Pw[rl * 72 + 48 + lr] = (bf16)p3;
        }
        CBAR();
        // PV: Ostrip_h += Pstrip @ V_h
#pragma unroll
        for (int kk = 0; kk < 2; ++kk) {
            bf16x8 pa = *(const bf16x8*)&Pw[lr * 72 + kk * 32 + lk * 8];
#pragma unroll
            for (int ni = 0; ni < 2; ++ni) {
                bf16x8 vb = *(const bf16x8*)&vt[(h * 32 + ni * 16 + lr) * 72 + kk * 32 + lk * 8];
                oacc[h][ni] = __builtin_amdgcn_mfma_f32_16x16x32_bf16(pa, vb, oacc[h][ni], 0, 0, 0);
            }
        }
        CBAR();
    }

    // ---- O -> Ost (overlay qall, own strip only), normalize here
#pragma unroll
    for (int h = 0; h < 3; ++h)
#pragma unroll
        for (int ni = 0; ni < 2; ++ni)
#pragma unroll
            for (int e = 0; e < 4; ++e)
                Ost[(w * 16 + lk * 4 + e) * 104 + h * 32 + ni * 16 + lr]
                    = (bf16)(oacc[h][ni][e] * inv[h][e]);
    __syncthreads();   // B2 (kall/vt reads done in all waves; fin overlay safe)

    // ---- proj: wave strip x [96x96]; 18 MFMA; fin overlays kall+vt
    {
        f32x4 pacc[6];
#pragma unroll
        for (int ni = 0; ni < 6; ++ni) pacc[ni] = (f32x4){0.f, 0.f, 0.f, 0.f};
#pragma unroll
        for (int k = 0; k < 3; ++k) {
            bf16x8 a = *(const bf16x8*)&Ost[(w * 16 + lr) * 104 + k * 32 + lk * 8];
#pragma unroll
            for (int ni = 0; ni < 6; ++ni) {
                bf16x8 wb = *(const bf16x8*)&woutT[(ni * 16 + lr) * 96 + k * 32 + lk * 8];
                pacc[ni] = __builtin_amdgcn_mfma_f32_16x16x32_bf16(a, wb, pacc[ni], 0, 0, 0);
            }
        }
#pragma unroll
        for (int ni = 0; ni < 6; ++ni)
#pragma unroll
            for (int e = 0; e < 4; ++e)
                fin[(w * 16 + lk * 4 + e) * 101 + ni * 16 + lr] = pacc[ni][e] + bo[ni];
    }
    __syncthreads();   // B3

    // ---- store [b, c, H, W]; t = lane fixed, channel marches
    {
        const int t = lane;
        if (t < 49) {
            const int off = (row0 + t / 7) * 56 + col0 + t % 7;
            float* ob = out + (size_t)(b * 96 + w * 24) * 3136 + off;
            const float* fr = fin + t * 101 + w * 24;
#pragma unroll
            for (int j = 0; j < 24; ++j)
                ob[(size_t)j * 3136] = fr[j];
        }
    }
}

extern "C" void kernel_launch(void* const* d_in, const int* in_sizes, int n_in,
                              void* d_out, int out_size, void* d_ws, size_t ws_size,
                              hipStream_t stream) {
    const float* x    = (const float*)d_in[0];
    const float* wqkv = (const float*)d_in[1];
    const float* pos  = (const float*)d_in[2];
    const float* wout = (const float*)d_in[3];
    const float* bout = (const float*)d_in[4];
    float* outp = (float*)d_out;

    bf16*  xwin  = (bf16*)((char*)d_ws + XWIN_OFF);
    bf16*  wqkvT = (bf16*)((char*)d_ws + WQKVT_OFF);
    bf16*  woutT = (bf16*)((char*)d_ws + WOUTT_OFF);
    float* biasC = (float*)((char*)d_ws + BIASC_OFF);

    pre<<<dim3(516), dim3(512), 0, stream>>>(x, wqkv, pos, wout,
                                             xwin, wqkvT, woutT, biasC);
    winattn<<<dim3(4096), dim3(256), 0, stream>>>(xwin, bout, wqkvT, woutT,
                                                  biasC, outp);
}

// Round 13
// 132.205 us; speedup vs baseline: 1.0668x; 1.0668x over previous
//
#include <hip/hip_runtime.h>

typedef __bf16 bf16;
typedef __bf16 bf16x4 __attribute__((ext_vector_type(4)));
typedef __bf16 bf16x8 __attribute__((ext_vector_type(8)));
typedef float  f32x4  __attribute__((ext_vector_type(4)));

#define SCALE 0.17677669529663687f  // 32^-0.5

// ws layout (bytes)
#define XWIN_OFF  0                  // bf16 [64 b][64 win][64 tok][96 ch]
#define WQKVT_OFF 50331648           // bf16 [288][96] (q cols pre-scaled)
#define WOUTT_OFF 50386944           // bf16 [96][96] transposed
#define BIASC_OFF 50405376           // f32 [3 h][4 ni][4 w][64 lane][4 e] C-frag layout

#define CBAR() asm volatile("" ::: "memory")

// 16-lane (DPP row) all-reduce; ctrl must be a compile-time constant.
template <int CTRL>
__device__ __forceinline__ float dpp_mv(float x) {
    return __int_as_float(__builtin_amdgcn_update_dpp(
        0, __float_as_int(x), CTRL, 0xF, 0xF, true));
}
__device__ __forceinline__ float row16_max(float m) {
    m = fmaxf(m, dpp_mv<0xB1>(m));   // quad_perm [1,0,3,2]
    m = fmaxf(m, dpp_mv<0x4E>(m));   // quad_perm [2,3,0,1]
    m = fmaxf(m, dpp_mv<0x124>(m));  // row_ror:4
    m = fmaxf(m, dpp_mv<0x128>(m));  // row_ror:8
    return m;
}
__device__ __forceinline__ float row16_sum(float s) {
    s += dpp_mv<0xB1>(s);
    s += dpp_mv<0x4E>(s);
    s += dpp_mv<0x124>(s);
    s += dpp_mv<0x128>(s);
    return s;
}

// ---- im2win (blocks 0..511) + weight/bias prep (blocks 512..515)
__global__ __launch_bounds__(512)
void pre(const float* __restrict__ x, const float* __restrict__ wqkv,
         const float* __restrict__ pos, const float* __restrict__ wout,
         bf16* __restrict__ xwin, bf16* __restrict__ wqkvT,
         bf16* __restrict__ woutT, float* __restrict__ biasC)
{
    __shared__ bf16 xs[392 * 50];
    if (blockIdx.x < 512) {
        const int tid = threadIdx.x;
        const int b = blockIdx.x >> 3, wh = blockIdx.x & 7;
        const float* xb = x + (size_t)b * 96 * 3136 + wh * 7 * 56;
        bf16* xo = xwin + ((size_t)b * 64 + wh * 8) * 64 * 96;
        for (int c0 = 0; c0 < 96; c0 += 48) {
            if (c0) __syncthreads();
            for (int i = tid; i < 48 * 392; i += 512) {
                int c = i / 392, t = i - c * 392;
                xs[t * 50 + c] = (bf16)xb[(size_t)(c0 + c) * 3136 + t];
            }
            __syncthreads();
            for (int i = tid; i < 8 * 64 * 48; i += 512) {
                int c = i % 48;
                int wt = (i / 48) & 63;
                int win = i / (48 * 64);
                bf16 v = (bf16)0.f;
                if (wt < 49) v = xs[((wt / 7) * 56 + win * 7 + (wt % 7)) * 50 + c];
                xo[(win * 64 + wt) * 96 + c0 + c] = v;
            }
        }
    } else {
        int tid = (blockIdx.x - 512) * 512 + threadIdx.x;
        const int stride = 4 * 512;
        for (int i = tid; i < 288 * 96; i += stride) {
            int n = i / 96, c = i % 96;
            float v = wqkv[c * 288 + n];
            if (n < 96) v *= SCALE;
            wqkvT[i] = (bf16)v;
        }
        for (int i = tid; i < 96 * 96; i += stride) {
            int o = i / 96, c = i % 96;
            woutT[i] = (bf16)wout[c * 96 + o];
        }
        // biasC[h][ni][w][lane][e] at row=w*16+(lane>>4)*4+e, col=ni*16+(lane&15)
        for (int i = tid; i < 3 * 4 * 4 * 64 * 4; i += stride) {
            int e = i & 3, lane = (i >> 2) & 63, wv = (i >> 8) & 3, ni = (i >> 10) & 3, h = i >> 12;
            int row = wv * 16 + ((lane >> 4) << 2) + e;
            int col = ni * 16 + (lane & 15);
            float v;
            if (col >= 49) v = -1e30f;
            else if (row >= 49) v = 0.f;
            else {
                int ridx = ((col / 7) - (row / 7) + 6) * 13 + ((col % 7) - (row % 7) + 6);
                v = pos[ridx * 3 + h];
            }
            biasC[i] = v;
        }
    }
}

// One block (4 waves) per window; wave w owns token strip w*16..+15.
// LDS 40448 B -> 4 blocks/CU. XCD write-combining swizzle:
//   blkId = b*64 + ww*8 + wh  => the 8 ww-blocks of a window-row share
//   blkId%8 (same XCD) and are <=56 dispatch slots apart, so their 28 B
//   output segments merge into full lines in that XCD's L2.
__global__ __launch_bounds__(256, 4)
void winattn(const bf16* __restrict__ xwin, const float* __restrict__ bout,
             const bf16* __restrict__ wqkvT, const bf16* __restrict__ woutT,
             const float* __restrict__ biasC, float* __restrict__ out)
{
    __shared__ __align__(16) unsigned char smem[40448];
    bf16* qall = (bf16*)(smem);          // [64][104]
    bf16* kall = (bf16*)(smem + 13312);  // [64][104]
    bf16* vt   = (bf16*)(smem + 26624);  // [96][72]
    bf16* Ost  = (bf16*)(smem);          // overlay qall (own strip only)
    float* fin = (float*)(smem + 13312); // [64][101] f32, overlays kall+vt (post-B2)

    const int tid = threadIdx.x;
    const int w = tid >> 6, lane = tid & 63;
    const int lr = lane & 15, lk = lane >> 4;

    // ---- XCD write-combining decode
    const int blkraw = blockIdx.x;
    const int b  = blkraw >> 6;
    const int wh = blkraw & 7;
    const int ww = (blkraw >> 3) & 7;
    const int win = wh * 8 + ww;
    const int row0 = wh * 7, col0 = ww * 7;
    const bf16* xg = xwin + (size_t)(b * 64 + win) * 64 * 96;

    float bo[6];
#pragma unroll
    for (int ni = 0; ni < 6; ++ni) bo[ni] = bout[ni * 16 + lr];

    // ---- QKV: wave w = row strip; 3 groups of 6 ni tiles (g0=q, g1=k, g2=v)
    {
        bf16x8 a[3];
#pragma unroll
        for (int k = 0; k < 3; ++k)
            a[k] = *(const bf16x8*)&xg[(w * 16 + lr) * 96 + k * 32 + lk * 8];
#pragma unroll
        for (int g = 0; g < 3; ++g) {
            f32x4 acc[6];
#pragma unroll
            for (int j = 0; j < 6; ++j) acc[j] = (f32x4){0.f, 0.f, 0.f, 0.f};
#pragma unroll
            for (int k = 0; k < 3; ++k)
#pragma unroll
                for (int j = 0; j < 6; ++j) {
                    bf16x8 bb = *(const bf16x8*)&wqkvT[((g * 6 + j) * 16 + lr) * 96 + k * 32 + lk * 8];
                    acc[j] = __builtin_amdgcn_mfma_f32_16x16x32_bf16(a[k], bb, acc[j], 0, 0, 0);
                }
            if (g == 0) {
#pragma unroll
                for (int j = 0; j < 6; ++j)
#pragma unroll
                    for (int e = 0; e < 4; ++e)
                        qall[(w * 16 + lk * 4 + e) * 104 + j * 16 + lr] = (bf16)acc[j][e];
            } else if (g == 1) {
#pragma unroll
                for (int j = 0; j < 6; ++j)
#pragma unroll
                    for (int e = 0; e < 4; ++e)
                        kall[(w * 16 + lk * 4 + e) * 104 + j * 16 + lr] = (bf16)acc[j][e];
            } else {
#pragma unroll
                for (int j = 0; j < 6; ++j) {
                    bf16x4 pk;
#pragma unroll
                    for (int e = 0; e < 4; ++e) pk[e] = (bf16)acc[j][e];
                    *(bf16x4*)&vt[(j * 16 + lr) * 72 + w * 16 + lk * 4] = pk;
                }
            }
        }
    }
    // prefetch head-0 bias C-frags (latency covered by barrier)
    f32x4 bias0[4], bias1[4], bias2[4];
#pragma unroll
    for (int ni = 0; ni < 4; ++ni)
        bias0[ni] = *(const f32x4*)&biasC[(size_t)((0 * 4 + ni) * 4 + w) * 256 + lane * 4];
    __syncthreads();   // B1

    // ---- read Q A-frags for all heads; then P may overlay own qall strip
    bf16x8 qa[3];
#pragma unroll
    for (int h = 0; h < 3; ++h)
        qa[h] = *(const bf16x8*)&qall[(w * 16 + lr) * 104 + h * 32 + lk * 8];
    CBAR();   // in-order DS pipe handles the WAR vs Pw writes

    bf16* Pw = (bf16*)(smem + w * 3328);   // [16][72] inside own qall strip

    f32x4 oacc[3][2];
    float inv[3][4];
#pragma unroll
    for (int h = 0; h < 3; ++h)
#pragma unroll
        for (int ni = 0; ni < 2; ++ni) oacc[h][ni] = (f32x4){0.f, 0.f, 0.f, 0.f};

#pragma unroll
    for (int h = 0; h < 3; ++h) {
        // S = Q@K^T + bias (bias is the C-operand)
        f32x4 sacc[4];
        const f32x4* bc = (h == 0) ? bias0 : (h == 1) ? bias1 : bias2;
#pragma unroll
        for (int ni = 0; ni < 4; ++ni) {
            bf16x8 kb = *(const bf16x8*)&kall[(ni * 16 + lr) * 104 + h * 32 + lk * 8];
            sacc[ni] = __builtin_amdgcn_mfma_f32_16x16x32_bf16(qa[h], kb, bc[ni], 0, 0, 0);
        }
        // prefetch next head's bias (covered by softmax+PV)
        if (h == 0) {
#pragma unroll
            for (int ni = 0; ni < 4; ++ni)
                bias1[ni] = *(const f32x4*)&biasC[(size_t)((1 * 4 + ni) * 4 + w) * 256 + lane * 4];
        } else if (h == 1) {
#pragma unroll
            for (int ni = 0; ni < 4; ++ni)
                bias2[ni] = *(const f32x4*)&biasC[(size_t)((2 * 4 + ni) * 4 + w) * 256 + lane * 4];
        }
        // softmax over 64 cols: 4 regs local + DPP 16-lane all-reduce.
        // P stored UNNORMALIZED (<=1); inv folded into the Ost write.
#pragma unroll
        for (int e = 0; e < 4; ++e) {
            float s0 = sacc[0][e], s1 = sacc[1][e], s2 = sacc[2][e], s3 = sacc[3][e];
            float m = row16_max(fmaxf(fmaxf(s0, s1), fmaxf(s2, s3)));
            float p0 = __expf(s0 - m), p1 = __expf(s1 - m);
            float p2 = __expf(s2 - m), p3 = __expf(s3 - m);
            float s = row16_sum((p0 + p1) + (p2 + p3));
            inv[h][e] = __builtin_amdgcn_rcpf(s);
            int rl = lk * 4 + e;
            Pw[rl * 72 + lr]      = (bf16)p0;
            Pw[rl * 72 + 16 + lr] = (bf16)p1;
            Pw[rl * 72 + 32 + lr] = (bf16)p2;
            Pw[rl * 72 + 48 + lr] = (bf16)p3;
        }
        CBAR();
        // PV: Ostrip_h += Pstrip @ V_h
#pragma unroll
        for (int kk = 0; kk < 2; ++kk) {
            bf16x8 pa = *(const bf16x8*)&Pw[lr * 72 + kk * 32 + lk * 8];
#pragma unroll
            for (int ni = 0; ni < 2; ++ni) {
                bf16x8 vb = *(const bf16x8*)&vt[(h * 32 + ni * 16 + lr) * 72 + kk * 32 + lk * 8];
                oacc[h][ni] = __builtin_amdgcn_mfma_f32_16x16x32_bf16(pa, vb, oacc[h][ni], 0, 0, 0);
            }
        }
        CBAR();
    }

    // ---- O -> Ost (overlay qall, own strip only), normalize here
#pragma unroll
    for (int h = 0; h < 3; ++h)
#pragma unroll
        for (int ni = 0; ni < 2; ++ni)
#pragma unroll
            for (int e = 0; e < 4; ++e)
                Ost[(w * 16 + lk * 4 + e) * 104 + h * 32 + ni * 16 + lr]
                    = (bf16)(oacc[h][ni][e] * inv[h][e]);
    __syncthreads();   // B2 (kall/vt reads done in all waves; fin overlay safe)

    // ---- proj: wave strip x [96x96]; 18 MFMA; fin overlays kall+vt
    {
        f32x4 pacc[6];
#pragma unroll
        for (int ni = 0; ni < 6; ++ni) pacc[ni] = (f32x4){0.f, 0.f, 0.f, 0.f};
#pragma unroll
        for (int k = 0; k < 3; ++k) {
            bf16x8 a = *(const bf16x8*)&Ost[(w * 16 + lr) * 104 + k * 32 + lk * 8];
#pragma unroll
            for (int ni = 0; ni < 6; ++ni) {
                bf16x8 wb = *(const bf16x8*)&woutT[(ni * 16 + lr) * 96 + k * 32 + lk * 8];
                pacc[ni] = __builtin_amdgcn_mfma_f32_16x16x32_bf16(a, wb, pacc[ni], 0, 0, 0);
            }
        }
#pragma unroll
        for (int ni = 0; ni < 6; ++ni)
#pragma unroll
            for (int e = 0; e < 4; ++e)
                fin[(w * 16 + lk * 4 + e) * 101 + ni * 16 + lr] = pacc[ni][e] + bo[ni];
    }
    __syncthreads();   // B3

    // ---- store [b, c, H, W]; t = lane fixed, channel marches
    {
        const int t = lane;
        if (t < 49) {
            const int off = (row0 + t / 7) * 56 + col0 + t % 7;
            float* ob = out + (size_t)(b * 96 + w * 24) * 3136 + off;
            const float* fr = fin + t * 101 + w * 24;
#pragma unroll
            for (int j = 0; j < 24; ++j)
                ob[(size_t)j * 3136] = fr[j];
        }
    }
}

extern "C" void kernel_launch(void* const* d_in, const int* in_sizes, int n_in,
                              void* d_out, int out_size, void* d_ws, size_t ws_size,
                              hipStream_t stream) {
    const float* x    = (const float*)d_in[0];
    const float* wqkv = (const float*)d_in[1];
    const float* pos  = (const float*)d_in[2];
    const float* wout = (const float*)d_in[3];
    const float* bout = (const float*)d_in[4];
    float* outp = (float*)d_out;

    bf16*  xwin  = (bf16*)((char*)d_ws + XWIN_OFF);
    bf16*  wqkvT = (bf16*)((char*)d_ws + WQKVT_OFF);
    bf16*  woutT = (bf16*)((char*)d_ws + WOUTT_OFF);
    float* biasC = (float*)((char*)d_ws + BIASC_OFF);

    pre<<<dim3(516), dim3(512), 0, stream>>>(x, wqkv, pos, wout,
                                             xwin, wqkvT, woutT, biasC);
    winattn<<<dim3(4096), dim3(256), 0, stream>>>(xwin, bout, wqkvT, woutT,
                                                  biasC, outp);
}

// Round 17
// 97.141 us; speedup vs baseline: 1.4519x; 1.3610x over previous
//
#include <hip/hip_runtime.h>

typedef __bf16 bf16;
typedef __bf16 bf16x4 __attribute__((ext_vector_type(4)));
typedef __bf16 bf16x8 __attribute__((ext_vector_type(8)));
typedef float  f32x4  __attribute__((ext_vector_type(4)));

#define SCALE 0.17677669529663687f  // 32^-0.5

// ws layout (bytes)
#define XWIN_OFF  0                  // bf16 [64 b][64 win][64 tok][96 ch]
#define WQKVT_OFF 50331648           // bf16 [288][96] (q cols pre-scaled)
#define WOUTT_OFF 50386944           // bf16 [96][96] transposed
#define BIASC_OFF 50405376           // f32 [3 h][4 ni][4 w][64 lane][4 e] C-frag layout

#define CBAR() asm volatile("" ::: "memory")

// 16-lane (DPP row) all-reduce; ctrl must be a compile-time constant.
template <int CTRL>
__device__ __forceinline__ float dpp_mv(float x) {
    return __int_as_float(__builtin_amdgcn_update_dpp(
        0, __float_as_int(x), CTRL, 0xF, 0xF, true));
}
__device__ __forceinline__ float row16_max(float m) {
    m = fmaxf(m, dpp_mv<0xB1>(m));   // quad_perm [1,0,3,2]
    m = fmaxf(m, dpp_mv<0x4E>(m));   // quad_perm [2,3,0,1]
    m = fmaxf(m, dpp_mv<0x124>(m));  // row_ror:4
    m = fmaxf(m, dpp_mv<0x128>(m));  // row_ror:8
    return m;
}
__device__ __forceinline__ float row16_sum(float s) {
    s += dpp_mv<0xB1>(s);
    s += dpp_mv<0x4E>(s);
    s += dpp_mv<0x124>(s);
    s += dpp_mv<0x128>(s);
    return s;
}

// ---- im2win (blocks 0..511) + weight/bias prep (blocks 512..515)
__global__ __launch_bounds__(512)
void pre(const float* __restrict__ x, const float* __restrict__ wqkv,
         const float* __restrict__ pos, const float* __restrict__ wout,
         bf16* __restrict__ xwin, bf16* __restrict__ wqkvT,
         bf16* __restrict__ woutT, float* __restrict__ biasC)
{
    __shared__ bf16 xs[392 * 50];
    if (blockIdx.x < 512) {
        const int tid = threadIdx.x;
        const int b = blockIdx.x >> 3, wh = blockIdx.x & 7;
        const float* xb = x + (size_t)b * 96 * 3136 + wh * 7 * 56;
        bf16* xo = xwin + ((size_t)b * 64 + wh * 8) * 64 * 96;
        for (int c0 = 0; c0 < 96; c0 += 48) {
            if (c0) __syncthreads();
            for (int i = tid; i < 48 * 392; i += 512) {
                int c = i / 392, t = i - c * 392;
                xs[t * 50 + c] = (bf16)xb[(size_t)(c0 + c) * 3136 + t];
            }
            __syncthreads();
            for (int i = tid; i < 8 * 64 * 48; i += 512) {
                int c = i % 48;
                int wt = (i / 48) & 63;
                int win = i / (48 * 64);
                bf16 v = (bf16)0.f;
                if (wt < 49) v = xs[((wt / 7) * 56 + win * 7 + (wt % 7)) * 50 + c];
                xo[(win * 64 + wt) * 96 + c0 + c] = v;
            }
        }
    } else {
        int tid = (blockIdx.x - 512) * 512 + threadIdx.x;
        const int stride = 4 * 512;
        for (int i = tid; i < 288 * 96; i += stride) {
            int n = i / 96, c = i % 96;
            float v = wqkv[c * 288 + n];
            if (n < 96) v *= SCALE;
            wqkvT[i] = (bf16)v;
        }
        for (int i = tid; i < 96 * 96; i += stride) {
            int o = i / 96, c = i % 96;
            woutT[i] = (bf16)wout[c * 96 + o];
        }
        // biasC[h][ni][w][lane][e] at row=w*16+(lane>>4)*4+e, col=ni*16+(lane&15)
        for (int i = tid; i < 3 * 4 * 4 * 64 * 4; i += stride) {
            int e = i & 3, lane = (i >> 2) & 63, wv = (i >> 8) & 3, ni = (i >> 10) & 3, h = i >> 12;
            int row = wv * 16 + ((lane >> 4) << 2) + e;
            int col = ni * 16 + (lane & 15);
            float v;
            if (col >= 49) v = -1e30f;
            else if (row >= 49) v = 0.f;
            else {
                int ridx = ((col / 7) - (row / 7) + 6) * 13 + ((col % 7) - (row % 7) + 6);
                v = pos[ridx * 3 + h];
            }
            biasC[i] = v;
        }
    }
}

// One block (4 waves) per window. QKV/proj: wave owns ni COLUMN tiles
// (weight B-frags loaded once per BLOCK, not once per wave). Attention
// core: wave owns token strip w*16..+15. LDS 40448 B -> 4 blocks/CU.
// XCD write-combining swizzle: blkId = b*64 + ww*8 + wh.
__global__ __launch_bounds__(256, 4)
void winattn(const bf16* __restrict__ xwin, const float* __restrict__ bout,
             const bf16* __restrict__ wqkvT, const bf16* __restrict__ woutT,
             const float* __restrict__ biasC, float* __restrict__ out)
{
    __shared__ __align__(16) unsigned char smem[40448];
    bf16* qall = (bf16*)(smem);          // [64][104]
    bf16* kall = (bf16*)(smem + 13312);  // [64][104]
    bf16* vt   = (bf16*)(smem + 26624);  // [96][72]
    bf16* Ost  = (bf16*)(smem);          // overlay qall
    float* fin = (float*)(smem + 13312); // [64][101] f32, overlays kall+vt (post-B2)

    const int tid = threadIdx.x;
    const int w = tid >> 6, lane = tid & 63;
    const int lr = lane & 15, lk = lane >> 4;

    // ---- XCD write-combining decode
    const int blkraw = blockIdx.x;
    const int b  = blkraw >> 6;
    const int wh = blkraw & 7;
    const int ww = (blkraw >> 3) & 7;
    const int win = wh * 8 + ww;
    const int row0 = wh * 7, col0 = ww * 7;
    const bf16* xg = xwin + (size_t)(b * 64 + win) * 64 * 96;

    // ---- QKV: wave w owns ni tiles (5,5,4,4 of 18); all 4 row strips.
    {
        bf16x8 a[4][3];
#pragma unroll
        for (int mi = 0; mi < 4; ++mi)
#pragma unroll
            for (int k = 0; k < 3; ++k)
                a[mi][k] = *(const bf16x8*)&xg[(mi * 16 + lr) * 96 + k * 32 + lk * 8];
        const int ni0  = (w < 2) ? w * 5 : 10 + (w - 2) * 4;
        const int ncnt = (w < 2) ? 5 : 4;
#pragma unroll
        for (int j = 0; j < 5; ++j) {
            if (j < ncnt) {
                const int ni = ni0 + j;
                f32x4 acc[4];
#pragma unroll
                for (int mi = 0; mi < 4; ++mi) acc[mi] = (f32x4){0.f, 0.f, 0.f, 0.f};
#pragma unroll
                for (int k = 0; k < 3; ++k) {
                    bf16x8 bb = *(const bf16x8*)&wqkvT[(ni * 16 + lr) * 96 + k * 32 + lk * 8];
#pragma unroll
                    for (int mi = 0; mi < 4; ++mi)
                        acc[mi] = __builtin_amdgcn_mfma_f32_16x16x32_bf16(a[mi][k], bb, acc[mi], 0, 0, 0);
                }
                if (ni < 6) {
#pragma unroll
                    for (int mi = 0; mi < 4; ++mi)
#pragma unroll
                        for (int e = 0; e < 4; ++e)
                            qall[(mi * 16 + lk * 4 + e) * 104 + ni * 16 + lr] = (bf16)acc[mi][e];
                } else if (ni < 12) {
#pragma unroll
                    for (int mi = 0; mi < 4; ++mi)
#pragma unroll
                        for (int e = 0; e < 4; ++e)
                            kall[(mi * 16 + lk * 4 + e) * 104 + (ni - 6) * 16 + lr] = (bf16)acc[mi][e];
                } else {
#pragma unroll
                    for (int mi = 0; mi < 4; ++mi) {
                        bf16x4 pk;
#pragma unroll
                        for (int e = 0; e < 4; ++e) pk[e] = (bf16)acc[mi][e];
                        *(bf16x4*)&vt[((ni - 12) * 16 + lr) * 72 + mi * 16 + lk * 4] = pk;
                    }
                }
            }
        }
    }
    // prefetch head-0 bias C-frags (latency covered by barrier)
    f32x4 bias0[4], bias1[4], bias2[4];
#pragma unroll
    for (int ni = 0; ni < 4; ++ni)
        bias0[ni] = *(const f32x4*)&biasC[(size_t)((0 * 4 + ni) * 4 + w) * 256 + lane * 4];
    __syncthreads();   // B1

    // ---- read Q A-frags for all heads; then P may overlay own qall strip
    bf16x8 qa[3];
#pragma unroll
    for (int h = 0; h < 3; ++h)
        qa[h] = *(const bf16x8*)&qall[(w * 16 + lr) * 104 + h * 32 + lk * 8];
    CBAR();   // in-order DS pipe handles the WAR vs Pw writes

    bf16* Pw = (bf16*)(smem + w * 3328);   // [16][72] inside own qall strip

    f32x4 oacc[3][2];
    float inv[3][4];
#pragma unroll
    for (int h = 0; h < 3; ++h)
#pragma unroll
        for (int ni = 0; ni < 2; ++ni) oacc[h][ni] = (f32x4){0.f, 0.f, 0.f, 0.f};

#pragma unroll
    for (int h = 0; h < 3; ++h) {
        // S = Q@K^T + bias (bias is the C-operand)
        f32x4 sacc[4];
        const f32x4* bc = (h == 0) ? bias0 : (h == 1) ? bias1 : bias2;
#pragma unroll
        for (int ni = 0; ni < 4; ++ni) {
            bf16x8 kb = *(const bf16x8*)&kall[(ni * 16 + lr) * 104 + h * 32 + lk * 8];
            sacc[ni] = __builtin_amdgcn_mfma_f32_16x16x32_bf16(qa[h], kb, bc[ni], 0, 0, 0);
        }
        // prefetch next head's bias (covered by softmax+PV)
        if (h == 0) {
#pragma unroll
            for (int ni = 0; ni < 4; ++ni)
                bias1[ni] = *(const f32x4*)&biasC[(size_t)((1 * 4 + ni) * 4 + w) * 256 + lane * 4];
        } else if (h == 1) {
#pragma unroll
            for (int ni = 0; ni < 4; ++ni)
                bias2[ni] = *(const f32x4*)&biasC[(size_t)((2 * 4 + ni) * 4 + w) * 256 + lane * 4];
        }
        // softmax over 64 cols: 4 regs local + DPP 16-lane all-reduce.
        // P stored UNNORMALIZED (<=1); inv folded into the Ost write.
#pragma unroll
        for (int e = 0; e < 4; ++e) {
            float s0 = sacc[0][e], s1 = sacc[1][e], s2 = sacc[2][e], s3 = sacc[3][e];
            float m = row16_max(fmaxf(fmaxf(s0, s1), fmaxf(s2, s3)));
            float p0 = __expf(s0 - m), p1 = __expf(s1 - m);
            float p2 = __expf(s2 - m), p3 = __expf(s3 - m);
            float s = row16_sum((p0 + p1) + (p2 + p3));
            inv[h][e] = __builtin_amdgcn_rcpf(s);
            int rl = lk * 4 + e;
            Pw[rl * 72 + lr]      = (bf16)p0;
            Pw[rl * 72 + 16 + lr] = (bf16)p1;
            Pw[rl * 72 + 32 + lr] = (bf16)p2;
            Pw[rl * 72 + 48 + lr] = (bf16)p3;
        }
        CBAR();
        // PV: Ostrip_h += Pstrip @ V_h
#pragma unroll
        for (int kk = 0; kk < 2; ++kk) {
            bf16x8 pa = *(const bf16x8*)&Pw[lr * 72 + kk * 32 + lk * 8];
#pragma unroll
            for (int ni = 0; ni < 2; ++ni) {
                bf16x8 vb = *(const bf16x8*)&vt[(h * 32 + ni * 16 + lr) * 72 + kk * 32 + lk * 8];
                oacc[h][ni] = __builtin_amdgcn_mfma_f32_16x16x32_bf16(pa, vb, oacc[h][ni], 0, 0, 0);
            }
        }
        CBAR();
    }

    // ---- O -> Ost (overlay qall, own strip only), normalize here
#pragma unroll
    for (int h = 0; h < 3; ++h)
#pragma unroll
        for (int ni = 0; ni < 2; ++ni)
#pragma unroll
            for (int e = 0; e < 4; ++e)
                Ost[(w * 16 + lk * 4 + e) * 104 + h * 32 + ni * 16 + lr]
                    = (bf16)(oacc[h][ni][e] * inv[h][e]);
    __syncthreads();   // B2 (kall/vt reads done in all waves; fin overlay safe)

    // ---- proj: wave w owns ni tiles {w,w+4}/{w}; all 4 row strips.
    {
        const int pcnt = (w < 2) ? 2 : 1;
#pragma unroll
        for (int j = 0; j < 2; ++j) {
            if (j < pcnt) {
                const int ni = w + j * 4;
                const float bo = bout[ni * 16 + lr];
                f32x4 pacc[4];
#pragma unroll
                for (int mi = 0; mi < 4; ++mi) pacc[mi] = (f32x4){0.f, 0.f, 0.f, 0.f};
#pragma unroll
                for (int k = 0; k < 3; ++k) {
                    bf16x8 wb = *(const bf16x8*)&woutT[(ni * 16 + lr) * 96 + k * 32 + lk * 8];
#pragma unroll
                    for (int mi = 0; mi < 4; ++mi) {
                        bf16x8 as = *(const bf16x8*)&Ost[(mi * 16 + lr) * 104 + k * 32 + lk * 8];
                        pacc[mi] = __builtin_amdgcn_mfma_f32_16x16x32_bf16(as, wb, pacc[mi], 0, 0, 0);
                    }
                }
#pragma unroll
                for (int mi = 0; mi < 4; ++mi)
#pragma unroll
                    for (int e = 0; e < 4; ++e)
                        fin[(mi * 16 + lk * 4 + e) * 101 + ni * 16 + lr] = pacc[mi][e] + bo;
            }
        }
    }
    __syncthreads();   // B3

    // ---- store [b, c, H, W]; t = lane fixed, channel marches
    {
        const int t = lane;
        if (t < 49) {
            const int off = (row0 + t / 7) * 56 + col0 + t % 7;
            float* ob = out + (size_t)(b * 96 + w * 24) * 3136 + off;
            const float* fr = fin + t * 101 + w * 24;
#pragma unroll
            for (int j = 0; j < 24; ++j)
                ob[(size_t)j * 3136] = fr[j];
        }
    }
}

extern "C" void kernel_launch(void* const* d_in, const int* in_sizes, int n_in,
                              void* d_out, int out_size, void* d_ws, size_t ws_size,
                              hipStream_t stream) {
    const float* x    = (const float*)d_in[0];
    const float* wqkv = (const float*)d_in[1];
    const float* pos  = (const float*)d_in[2];
    const float* wout = (const float*)d_in[3];
    const float* bout = (const float*)d_in[4];
    float* outp = (float*)d_out;

    bf16*  xwin  = (bf16*)((char*)d_ws + XWIN_OFF);
    bf16*  wqkvT = (bf16*)((char*)d_ws + WQKVT_OFF);
    bf16*  woutT = (bf16*)((char*)d_ws + WOUTT_OFF);
    float* biasC = (float*)((char*)d_ws + BIASC_OFF);

    pre<<<dim3(516), dim3(512), 0, stream>>>(x, wqkv, pos, wout,
                                             xwin, wqkvT, woutT, biasC);
    winattn<<<dim3(4096), dim3(256), 0, stream>>>(xwin, bout, wqkvT, woutT,
                                                  biasC, outp);
}